// Round 7
// baseline (217.299 us; speedup 1.0000x reference)
//
#include <hip/hip_runtime.h>
#include <stdint.h>

// CSSA: B=32, H=W=64, C=64, heads=4, hd=16, strip windows 64x8 -> 256 windows.
// Round 12: r11 structure (block = (window, HEAD-PAIR), 512 blocks x 1024 thr,
// 16 waves; WRITE_SIZE measured EXACTLY ideal 33.5 MB -> 128B pair-ownership
// geometry proven) with three changes aimed at the realized-occupancy cliff
// (r9/r11 both pin at ~34% with >64KB LDS; theory: only 1 big-LDS WG co-resides):
//  1. LDS 71.2KB -> EXACTLY 64KB: K and V^T frag-blocked (per chunk x head
//     16x16 tiles, lane-linear 8B/lane reads = structural-minimum 4 dw/bank,
//     zero padding). Conv W/B moved to direct global loads (L2-broadcast).
//  2. Explicit cross-chunk kf/vf prefetch (LDS latency covered by MFMA+exp2
//     of the previous chunk).
//  3. Epilogue: tap indices + OOB masks hoisted out of the j-loop (~500 fewer
//     VALU cyc/thread).
// Frag-blocked layout, shorts: idx = c*512 + hh*256 + quad*64 + l15*4 + i
//   Kl: element (key=l15, d=quad*4+i) of chunk c, head hh
//   Vl: element (d=l15, key=c*16+quad*4+i)      (read addr == Kl's: foff+c*512)
// QK^T transposed (A=K,B=Q) so P's C-layout == K=16 B-frag layout: PV MFMA
// consumes P straight from registers (r6 structure, unchanged).

typedef __attribute__((ext_vector_type(4))) short          short4v;
typedef __attribute__((ext_vector_type(4))) float          f32x4;
typedef __attribute__((ext_vector_type(4))) unsigned short us4;
typedef __bf16 bf2_t __attribute__((ext_vector_type(2)));

__device__ __forceinline__ float bf2f(unsigned short u) {
    union { unsigned int i; float f; } x; x.i = ((unsigned int)u) << 16; return x.f;
}
__device__ __forceinline__ unsigned int pk2bf(float lo, float hi) {
#if __has_builtin(__builtin_amdgcn_cvt_pk_bf16_f32)
    union { bf2_t v; unsigned int u; } c;
    c.v = __builtin_amdgcn_cvt_pk_bf16_f32(lo, hi);     // 1 VALU op
    return c.u;
#else
    union { float f; unsigned int u; } a, b; a.f = lo; b.f = hi;
    return __builtin_amdgcn_perm(b.u + 0x8000u, a.u + 0x8000u, 0x07060302u);
#endif
}
__device__ __forceinline__ short4v pk4bf(float a, float b, float c, float d) {
    union { short4v s; unsigned int u[2]; } p;
    p.u[0] = pk2bf(a, b);
    p.u[1] = pk2bf(c, d);
    return p.s;
}

__global__ __launch_bounds__(1024, 4)
void CSSA_69355131896243_kernel(const float* __restrict__ qkv,
                                const float* __restrict__ wconv,
                                const float* __restrict__ bconv,
                                float* __restrict__ out)
{
    __shared__ unsigned short Kl[16384];   // 32768 B frag-blocked K bf16
    __shared__ unsigned short Vl[16384];   // 32768 B frag-blocked V^T bf16

    const int tid  = threadIdx.x;
    const int wave = tid >> 6, lane = tid & 63, quad = lane >> 4, l15 = lane & 15;

    // bid = x + 8p + 16y (x=0..7, p=pair, y=0..31): win = x*32+y. Pair-siblings
    // differ by 8 -> same XCD, adjacent dispatch -> concurrent.
    const int bid = blockIdx.x;
    const int p   = (bid >> 3) & 1;
    const int win = (bid & 7) * 32 + (bid >> 4);
    const int b   = win >> 3, wx = win & 7;
    const int pc  = p * 32;                      // pair's first channel

    const size_t ONE  = (size_t)32 * 4096 * 64;
    const size_t base = ((size_t)b * 4096 + (size_t)wx * 8) * 64;
    const float* gQ = qkv + base;
    const float* gK = qkv + ONE + base;
    const float* gV = qkv + 2 * ONE + base;

    // ---- stage pair's K + V^T, frag-blocked bf16 (32 channels) ----
    {
        const int c8 = tid & 7;              // 4-ch group -> ch pc+c8*4..+3
        const int t0 = tid >> 3;             // 128 tokens per round
        const int shh = c8 >> 2, dq = c8 & 3;
        #pragma unroll
        for (int r = 0; r < 4; ++r) {
            const int t = r * 128 + t0;
            const size_t goff = (size_t)(t >> 3) * 4096 + (size_t)(t & 7) * 64 + pc + c8 * 4;
            f32x4 kd = *(const f32x4*)(gK + goff);
            f32x4 vd = *(const f32x4*)(gV + goff);
            union { us4 v; unsigned int u[2]; } kb;
            kb.u[0] = pk2bf(kd[0], kd[1]);
            kb.u[1] = pk2bf(kd[2], kd[3]);
            // K: (key=t&15, d=dq*4+j) of chunk t>>4, head shh
            const int kidx = (t >> 4) * 512 + shh * 256 + dq * 64 + (t & 15) * 4;
            *(us4*)(&Kl[kidx]) = kb.v;
            // V: (d=dq*4+j, key=t): quad_key=(t>>2)&3, i=t&3
            const unsigned int v01 = pk2bf(vd[0], vd[1]);
            const unsigned int v23 = pk2bf(vd[2], vd[3]);
            const int vidx = (t >> 4) * 512 + shh * 256 + ((t >> 2) & 3) * 64 + dq * 16 + (t & 3);
            Vl[vidx +  0] = (unsigned short)(v01 & 0xffffu);
            Vl[vidx +  4] = (unsigned short)(v01 >> 16);
            Vl[vidx +  8] = (unsigned short)(v23 & 0xffffu);
            Vl[vidx + 12] = (unsigned short)(v23 >> 16);
        }
    }

    // ---- Q prefetch + pack (independent of LDS -> overlaps barrier wait) ----
    const float SCL = 0.25f * 1.44269504088896341f;   // scale*log2(e) folded in
    const int hh = wave & 1;             // head in pair
    const int hg = pc + hh * 16;         // head's first channel (global)
    const int q0 = (wave >> 1) * 64;
    short4v qf[4];   // B[k=d=quad*4+i][n=q=l15]
    #pragma unroll
    for (int t = 0; t < 4; ++t) {
        const int q = q0 + t * 16 + l15;
        f32x4 qv = *(const f32x4*)(gQ + (size_t)(q >> 3) * 4096 + (size_t)(q & 7) * 64 + hg + quad * 4);
        qf[t] = pk4bf(qv[0] * SCL, qv[1] * SCL, qv[2] * SCL, qv[3] * SCL);
    }
    __syncthreads();

    f32x4 acc[4];
    float lp[4];
    #pragma unroll
    for (int t = 0; t < 4; ++t) { acc[t] = (f32x4)0.0f; lp[t] = 0.0f; }

    // ---- main loop: 32 chunks x 16 keys, explicit cross-chunk prefetch ----
    const int foff = hh * 256 + quad * 64 + l15 * 4;   // same for Kl and Vl
    short4v kf = *(const short4v*)(&Kl[foff]);
    short4v vf = *(const short4v*)(&Vl[foff]);
    #pragma unroll 4
    for (int c = 0; c < 32; ++c) {
        const int nx = foff + ((c + 1) & 31) * 512;    // wrap: dead read at c=31
        const short4v kfn = *(const short4v*)(&Kl[nx]);
        const short4v vfn = *(const short4v*)(&Vl[nx]);
        #pragma unroll
        for (int t = 0; t < 4; ++t) {
            // s^T[key][q]: C row=quad*4+j -> key, col=l15 -> q
            f32x4 s = __builtin_amdgcn_mfma_f32_16x16x16bf16_1k(kf, qf[t], (f32x4)0.0f, 0, 0, 0);
            const float p0 = __builtin_amdgcn_exp2f(s[0]);
            const float p1 = __builtin_amdgcn_exp2f(s[1]);
            const float p2 = __builtin_amdgcn_exp2f(s[2]);
            const float p3 = __builtin_amdgcn_exp2f(s[3]);
            lp[t] += (p0 + p1) + (p2 + p3);
            // P C-layout == K=16 B-frag layout -> PV straight from registers
            acc[t] = __builtin_amdgcn_mfma_f32_16x16x16bf16_1k(vf, pk4bf(p0, p1, p2, p3), acc[t], 0, 0, 0);
        }
        kf = kfn; vf = vfn;
    }

    // ---- denominators: cross-quad reduce ----
    float linv[4];
    #pragma unroll
    for (int t = 0; t < 4; ++t) {
        float v = lp[t];
        v += __shfl_xor(v, 16, 64);
        v += __shfl_xor(v, 32, 64);
        linv[t] = __builtin_amdgcn_rcpf(v);
    }

    // ---- epilogue: conv W/B direct from global (2.3KB, L2-broadcast) ----
    float w9[4][9], bs4[4];
    #pragma unroll
    for (int j = 0; j < 4; ++j) {
        const int ch = hg + quad * 4 + j;
        #pragma unroll
        for (int o = 0; o < 9; ++o) w9[j][o] = wconv[ch * 9 + o];
        bs4[j] = bconv[ch];
    }
    // LePE from resident frag-blocked Vl; tap idx/masks hoisted out of j-loop
    #pragma unroll
    for (int t = 0; t < 4; ++t) {
        const int q = q0 + t * 16 + l15;
        const int y = q >> 3, x = l15 & 7;
        int  pidx[9];
        bool okm[9];
        #pragma unroll
        for (int dy = 0; dy < 3; ++dy) {
            const int yy = y + dy - 1;
            const bool oky = ((unsigned)yy < 64u);
            #pragma unroll
            for (int dx = 0; dx < 3; ++dx) {
                const int o  = dy * 3 + dx;
                const int xx = x + dx - 1;
                okm[o] = oky && ((unsigned)xx < 8u);
                const int tt = (q + (dy - 1) * 8 + (dx - 1)) & 511;   // masked if OOB
                // Vl element (d=quad*4+j, key=tt): + j*4 added in j-loop
                pidx[o] = (tt >> 4) * 512 + hh * 256 + ((tt >> 2) & 3) * 64 + quad * 16 + (tt & 3);
            }
        }
        #pragma unroll
        for (int j = 0; j < 4; ++j) {
            float lep = bs4[j];
            #pragma unroll
            for (int o = 0; o < 9; ++o)
                lep += (okm[o] ? w9[j][o] : 0.0f) * bf2f(Vl[pidx[o] + j * 4]);
            acc[t][j] = acc[t][j] * linv[t] + lep;
        }
    }
    float* gO = out + base;
    #pragma unroll
    for (int t = 0; t < 4; ++t) {
        const int q = q0 + t * 16 + l15;
        *(f32x4*)(gO + (size_t)(q >> 3) * 4096 + (size_t)(q & 7) * 64 + hg + quad * 4) = acc[t];
    }
}

extern "C" void kernel_launch(void* const* d_in, const int* in_sizes, int n_in,
                              void* d_out, int out_size, void* d_ws, size_t ws_size,
                              hipStream_t stream) {
    const float* qkv   = (const float*)d_in[0];
    const float* wconv = (const float*)d_in[1];
    const float* bconv = (const float*)d_in[2];
    float* outp = (float*)d_out;
    hipLaunchKernelGGL(CSSA_69355131896243_kernel, dim3(512), dim3(1024), 0, stream,
                       qkv, wconv, bconv, outp);
}

// Round 8
// 183.196 us; speedup vs baseline: 1.1862x; 1.1862x over previous
//
#include <hip/hip_runtime.h>
#include <stdint.h>

// CSSA: B=32, H=W=64, C=64, heads=4, hd=16, strip windows 64x8 -> 256 windows.
// Round 13: occupancy-first. Six rounds of evidence: traffic fixes (r11: WRITE
// exactly ideal 33.5MB) bought nothing; all 1024-thr configs pin at ~34% occ;
// both pipes <40% busy, BW ~10% -> stall-bound, currency = resident waves.
// Block = (window, head, Q-HALF): 2048 blocks x 512 thr (8 waves); wave w ->
// q-rows qh*256 + w*32 .. +31 (2 tiles). LDS = one head's K+V frag-blocked
// bf16 = 32KB (+0.7KB conv W/B) -> 4 blocks/CU (thread-capped 2048) =
// 32 waves/CU = 100% theoretical occupancy. Write-amp from 64B head-slices
// returns (~3x) -- ACCEPTED: r11 proved removing it is worth ~0 at 10% BW.
// All LDS patterns constructed conflict-free (4 dw/bank structural min):
//  - K frag-blocked [chunk][dq][m^(dq<<2)][4]: XOR swizzle on write AND read.
//  - V^T staged channel-major: lane=(d, tokgroup), 4 coalesced scalar loads
//    (16 lanes x 4B consecutive = full 64B lines) -> one us4 write (r12's
//    scalar-scatter staging was the 7.7M-conflict source).
// QK^T transposed (A=K,B=Q) so P's C-layout == K=16 B-frag layout: PV MFMA
// consumes P straight from registers (r6 structure). Epilogue = r6's lean
// inline form (no index arrays -> no spill; r12's 84MB WRITE smelled of it).

typedef __attribute__((ext_vector_type(4))) short          short4v;
typedef __attribute__((ext_vector_type(4))) float          f32x4;
typedef __attribute__((ext_vector_type(4))) unsigned short us4;
typedef __bf16 bf2_t __attribute__((ext_vector_type(2)));

__device__ __forceinline__ float bf2f(unsigned short u) {
    union { unsigned int i; float f; } x; x.i = ((unsigned int)u) << 16; return x.f;
}
__device__ __forceinline__ unsigned int pk2bf(float lo, float hi) {
#if __has_builtin(__builtin_amdgcn_cvt_pk_bf16_f32)
    union { bf2_t v; unsigned int u; } c;
    c.v = __builtin_amdgcn_cvt_pk_bf16_f32(lo, hi);     // 1 VALU op
    return c.u;
#else
    union { float f; unsigned int u; } a, b; a.f = lo; b.f = hi;
    return __builtin_amdgcn_perm(b.u + 0x8000u, a.u + 0x8000u, 0x07060302u);
#endif
}
__device__ __forceinline__ short4v pk4bf(float a, float b, float c, float d) {
    union { short4v s; unsigned int u[2]; } p;
    p.u[0] = pk2bf(a, b);
    p.u[1] = pk2bf(c, d);
    return p.s;
}

__global__ __launch_bounds__(512, 6)
void CSSA_69355131896243_kernel(const float* __restrict__ qkv,
                                const float* __restrict__ wconv,
                                const float* __restrict__ bconv,
                                float* __restrict__ out)
{
    __shared__ unsigned short Kl[8192];   // 16384 B frag-blocked K bf16
    __shared__ unsigned short Vl[8192];   // 16384 B frag-blocked V^T bf16
    __shared__ float Wl[144];             // head's 16x9 conv weights
    __shared__ float Bl[16];

    const int tid  = threadIdx.x;
    const int wave = tid >> 6, lane = tid & 63, quad = lane >> 4, l15 = lane & 15;

    // bid = x + 8*s + 64*y: x=0..7, s=(head,qh) 0..7, y=0..31. The 8 s-siblings
    // of a window are 8..56 apart -> same XCD slot, adjacent dispatch ->
    // shared K/V reads and head-sibling output sectors merge in L2.
    const int bid  = blockIdx.x;
    const int x    = bid & 7, s = (bid >> 3) & 7, y = bid >> 6;
    const int head = s & 3, qh = s >> 2;
    const int win  = x * 32 + y;
    const int b    = win >> 3, wx = win & 7;
    const int hc   = head * 16;

    const size_t ONE  = (size_t)32 * 4096 * 64;
    const size_t base = ((size_t)b * 4096 + (size_t)wx * 8) * 64;
    const float* gQ = qkv + base;
    const float* gK = qkv + ONE + base;
    const float* gV = qkv + 2 * ONE + base;

    // ---- stage K: thread=(t0=tid>>2, c4=tid&3), 128 tokens/round ----
    {
        const int c4 = tid & 3;
        const int t0 = tid >> 2;
        #pragma unroll
        for (int r = 0; r < 4; ++r) {
            const int t = r * 128 + t0;
            const size_t goff = (size_t)(t >> 3) * 4096 + (size_t)(t & 7) * 64 + hc + c4 * 4;
            f32x4 kd = *(const f32x4*)(gK + goff);
            union { us4 v; unsigned int u[2]; } kb;
            kb.u[0] = pk2bf(kd[0], kd[1]);
            kb.u[1] = pk2bf(kd[2], kd[3]);
            // element (key=t, ch=c4*4+j): chunk=t>>4, m=(t&15)^(c4<<2) swizzle
            const int kidx = (t >> 4) * 256 + c4 * 64 + ((t & 15) ^ (c4 << 2)) * 4;
            *(us4*)(&Kl[kidx]) = kb.v;
        }
        // ---- stage V^T channel-major: lane=(d=tid&15, g=tid>>4 + 32r) ----
        const int d = tid & 15;
        #pragma unroll
        for (int r = 0; r < 4; ++r) {
            const int g = (tid >> 4) + r * 32;          // token group, t=g*4+i
            const float* src = gV + (size_t)(g >> 1) * 4096 + (size_t)((g & 1) * 4) * 64 + hc + d;
            const float v0 = src[0], v1 = src[64], v2 = src[128], v3 = src[192];
            union { us4 v; unsigned int u[2]; } vb;
            vb.u[0] = pk2bf(v0, v1);
            vb.u[1] = pk2bf(v2, v3);
            // element (d, t): chunk=g>>2, m_v=g&3, i=t&3 contiguous
            const int vidx = (g >> 2) * 256 + (g & 3) * 64 + d * 4;
            *(us4*)(&Vl[vidx]) = vb.v;
        }
    }
    if (tid < 144) Wl[tid] = wconv[head * 144 + tid];
    if (tid < 16)  Bl[tid] = bconv[hc + tid];

    // ---- Q prefetch + pack (independent of LDS -> overlaps barrier wait) ----
    const float SCL = 0.25f * 1.44269504088896341f;   // scale*log2(e) folded in
    const int q0 = qh * 256 + wave * 32;
    short4v qf[2];   // B[k=d=quad*4+i][n=q=l15]
    #pragma unroll
    for (int t = 0; t < 2; ++t) {
        const int q = q0 + t * 16 + l15;
        f32x4 qv = *(const f32x4*)(gQ + (size_t)(q >> 3) * 4096 + (size_t)(q & 7) * 64 + hc + quad * 4);
        qf[t] = pk4bf(qv[0] * SCL, qv[1] * SCL, qv[2] * SCL, qv[3] * SCL);
    }
    __syncthreads();

    f32x4 acc[2];
    float lp[2];
    #pragma unroll
    for (int t = 0; t < 2; ++t) { acc[t] = (f32x4)0.0f; lp[t] = 0.0f; }

    // ---- main loop: 32 chunks x 16 keys, conflict-free b64 frag reads ----
    const int koff = quad * 64 + (l15 ^ (quad << 2)) * 4;   // K: swizzled m
    const int voff = quad * 64 + l15 * 4;                   // V: (d=l15, k=quad*4+i)
    #pragma unroll 4
    for (int c = 0; c < 32; ++c) {
        // K A-frag: A[m=key=l15][k=d=quad*4+i]
        const short4v kf = *(const short4v*)(&Kl[koff + c * 256]);
        // V A-frag: A[m=d=l15][k=key=quad*4+i]
        const short4v vf = *(const short4v*)(&Vl[voff + c * 256]);
        #pragma unroll
        for (int t = 0; t < 2; ++t) {
            // s^T[key][q]: C row=quad*4+j -> key, col=l15 -> q
            f32x4 sc = __builtin_amdgcn_mfma_f32_16x16x16bf16_1k(kf, qf[t], (f32x4)0.0f, 0, 0, 0);
            const float p0 = __builtin_amdgcn_exp2f(sc[0]);
            const float p1 = __builtin_amdgcn_exp2f(sc[1]);
            const float p2 = __builtin_amdgcn_exp2f(sc[2]);
            const float p3 = __builtin_amdgcn_exp2f(sc[3]);
            lp[t] += (p0 + p1) + (p2 + p3);
            // P C-layout == K=16 B-frag layout -> PV straight from registers
            acc[t] = __builtin_amdgcn_mfma_f32_16x16x16bf16_1k(vf, pk4bf(p0, p1, p2, p3), acc[t], 0, 0, 0);
        }
    }

    // ---- denominators: cross-quad reduce ----
    float linv[2];
    #pragma unroll
    for (int t = 0; t < 2; ++t) {
        float v = lp[t];
        v += __shfl_xor(v, 16, 64);
        v += __shfl_xor(v, 32, 64);
        linv[t] = __builtin_amdgcn_rcpf(v);
    }

    // ---- epilogue: LePE from resident frag-blocked Vl, normalize, store ----
    #pragma unroll
    for (int j = 0; j < 4; ++j) {
        const int dbase = quad * 16 + j * 4;       // d=quad*4+j -> d*4 in vidx
        float w9[9];
        #pragma unroll
        for (int o = 0; o < 9; ++o) w9[o] = Wl[(quad * 4 + j) * 9 + o];
        const float bs = Bl[quad * 4 + j];
        #pragma unroll
        for (int t = 0; t < 2; ++t) {
            const int q = q0 + t * 16 + l15;
            const int yy0 = q >> 3, xx0 = l15 & 7;
            float lep = bs;
            #pragma unroll
            for (int dy = 0; dy < 3; ++dy) {
                #pragma unroll
                for (int dx = 0; dx < 3; ++dx) {
                    const int yy = yy0 + dy - 1, xx = xx0 + dx - 1;
                    const bool ok = ((unsigned)yy < 64u) && ((unsigned)xx < 8u);
                    const int tt = (q + (dy - 1) * 8 + (dx - 1)) & 511;   // masked if OOB
                    const int vi = (tt >> 4) * 256 + ((tt >> 2) & 3) * 64 + dbase + (tt & 3);
                    lep += (ok ? w9[dy * 3 + dx] : 0.0f) * bf2f(Vl[vi]);
                }
            }
            acc[t][j] = acc[t][j] * linv[t] + lep;
        }
    }
    float* gO = out + base;
    #pragma unroll
    for (int t = 0; t < 2; ++t) {
        const int q = q0 + t * 16 + l15;
        *(f32x4*)(gO + (size_t)(q >> 3) * 4096 + (size_t)(q & 7) * 64 + hc + quad * 4) = acc[t];
    }
}

extern "C" void kernel_launch(void* const* d_in, const int* in_sizes, int n_in,
                              void* d_out, int out_size, void* d_ws, size_t ws_size,
                              hipStream_t stream) {
    const float* qkv   = (const float*)d_in[0];
    const float* wconv = (const float*)d_in[1];
    const float* bconv = (const float*)d_in[2];
    float* outp = (float*)d_out;
    hipLaunchKernelGGL(CSSA_69355131896243_kernel, dim3(2048), dim3(512), 0, stream,
                       qkv, wconv, bconv, outp);
}